// Round 3
// baseline (324.675 us; speedup 1.0000x reference)
//
#include <hip/hip_runtime.h>
#include <math.h>

#define HH 128
#define WW 128
#define HWSZ (HH * WW)
#define BB 2
#define COUT 128

typedef __bf16 bf16x8 __attribute__((ext_vector_type(8)));
typedef float f32x4 __attribute__((ext_vector_type(4)));
typedef short s16x8 __attribute__((ext_vector_type(8)));
typedef short s16x4 __attribute__((ext_vector_type(4)));
typedef unsigned short u16x4 __attribute__((ext_vector_type(4)));

// 4 bf16 from a row window starting at an even column (4-byte aligned)
struct __attribute__((aligned(4))) US4 { unsigned short u[4]; };

__device__ __forceinline__ short tobf(float f) {
  union { float f; unsigned u; } v; v.f = f;
  unsigned r = v.u + 0x7fffu + ((v.u >> 16) & 1u);  // RNE
  return (short)(r >> 16);
}
__device__ __forceinline__ float b2f(unsigned short u) {
  union { unsigned u; float f; } v; v.u = ((unsigned)u) << 16;
  return v.f;
}

// ---------------------------------------------------------------------------
// Weight prep: dst[o*dstStride + dstOff + k] = bf16(src[o*K+k] * inv[o])
// K stays in natural c-major order (k = c*9 + n).
// ---------------------------------------------------------------------------
__global__ __launch_bounds__(256) void prep_scale_kernel(
    const float* __restrict__ src, const float* __restrict__ g,
    const float* __restrict__ v, short* __restrict__ dst,
    int K, int dstStride, int dstOff) {
  int k = blockIdx.x * 256 + threadIdx.x;
  int o = blockIdx.y;
  if (k >= K) return;
  float inv = g[o] / sqrtf(v[o] + 1e-5f);
  dst[(size_t)o * dstStride + dstOff + k] = tobf(src[(size_t)o * K + k] * inv);
}

// Offset-conv weights: n-major remap (offconv keeps chunk-uniform n), M pad 32
__global__ __launch_bounds__(256) void prep_off_kernel(const float* __restrict__ src,
                                                       short* __restrict__ dst,
                                                       int K, int Cin) {
  int k = blockIdx.x * 256 + threadIdx.x;
  int o = blockIdx.y;  // 0..31
  if (k >= K) return;
  int col = (k % 9) * Cin + (k / 9);
  dst[(size_t)o * K + col] = (o < 18) ? tobf(src[(size_t)o * K + k]) : (short)0;
}

// Epilogue constants: cb1 = beta1; cb2 = beta2 + id_b*inv3 + beta3
__global__ __launch_bounds__(128) void prep_bias_kernel(
    const float* b1, const float* m1, const float* g1, const float* v1,
    const float* b2, const float* m2, const float* g2, const float* v2,
    const float* b3, const float* m3, const float* g3, const float* v3,
    const float* idb, float* cb1, float* cb2) {
  int o = threadIdx.x;
  float inv1 = g1[o] / sqrtf(v1[o] + 1e-5f);
  float inv2 = g2[o] / sqrtf(v2[o] + 1e-5f);
  float inv3 = g3[o] / sqrtf(v3[o] + 1e-5f);
  cb1[o] = b1[o] - m1[o] * inv1;
  cb2[o] = (b2[o] - m2[o] * inv2) + idb[o] * inv3 + (b3[o] - m3[o] * inv3);
}

// Cast x (fp32) -> bf16 planes, float4 -> 4x bf16 per thread
__global__ __launch_bounds__(256) void xcast_kernel(const float* __restrict__ src,
                                                    unsigned short* __restrict__ dst,
                                                    int n4) {
  int i = blockIdx.x * 256 + threadIdx.x;
  if (i >= n4) return;
  float4 v = ((const float4*)src)[i];
  u16x4 o;
  o.x = (unsigned short)tobf(v.x); o.y = (unsigned short)tobf(v.y);
  o.z = (unsigned short)tobf(v.z); o.w = (unsigned short)tobf(v.w);
  ((u16x4*)dst)[i] = o;
}

// ---------------------------------------------------------------------------
// Offset conv as MFMA GEMM on bf16 input planes. Block: 64 px x 32 M,
// 512 thr = 8 waves. K n-major -> per 32-chunk, tap position n is uniform.
// XCD swizzle: each XCD covers 32 contiguous y rows for L2 row reuse.
// ---------------------------------------------------------------------------
__global__ __launch_bounds__(512, 4) void offconv_mfma_kernel(
    const unsigned short* __restrict__ in, const short* __restrict__ woff,
    const float* __restrict__ offb, float* __restrict__ off, int cshift) {
  __shared__ short wlds[32 * 40];
  __shared__ short vlds[64 * 40];
  const int tid = threadIdx.x;
  const int lane = tid & 63, wv = tid >> 6;
  const int pb = ((blockIdx.x & 7) << 6) | (blockIdx.x >> 3);  // XCD swizzle
  const int pix0 = pb << 6;
  const int x0 = pix0 & 127, y = (pix0 >> 7) & 127, b = pix0 >> 14;
  const int Cin = 1 << cshift;
  const int Kc = 9 << cshift;
  const unsigned short* inb = in + (size_t)b * Cin * HWSZ;
  const int p = lane, kb = wv;
  const int l15 = lane & 15, quad = lane >> 4;
  const int ptile = wv & 3, otile = wv >> 2;

  f32x4 acc = {0.f, 0.f, 0.f, 0.f};

  for (int k0 = 0; k0 < Kc; k0 += 32) {
    s16x8 wreg;
    if (tid < 128) wreg = *(const s16x8*)&woff[(size_t)(tid >> 2) * Kc + k0 + (tid & 3) * 8];
    int n = k0 >> cshift;
    int dy = n / 3 - 1, dx = n % 3 - 1;
    int yy = y + dy;
    int xx = x0 + p + dx;
    bool okx = ((unsigned)yy < (unsigned)HH) && ((unsigned)xx < (unsigned)WW);
    int c0 = (k0 & (Cin - 1)) + kb * 4;
    const unsigned short* pl = inb + (size_t)c0 * HWSZ + yy * WW + xx;
    s16x4 pk;
#pragma unroll
    for (int i = 0; i < 4; i++) pk[i] = okx ? (short)pl[(size_t)i * HWSZ] : (short)0;
    __syncthreads();
    if (tid < 128) *(s16x8*)&wlds[(tid >> 2) * 40 + (tid & 3) * 8] = wreg;
    *(s16x4*)&vlds[p * 40 + kb * 4] = pk;
    __syncthreads();
    bf16x8 bfr = *(const bf16x8*)&vlds[(ptile * 16 + l15) * 40 + quad * 8];
    bf16x8 afr = *(const bf16x8*)&wlds[(otile * 16 + l15) * 40 + quad * 8];
    acc = __builtin_amdgcn_mfma_f32_16x16x32_bf16(afr, bfr, acc, 0, 0, 0);
  }
#pragma unroll
  for (int r = 0; r < 4; r++) {
    int o = otile * 16 + quad * 4 + r;
    if (o < 18)
      off[(size_t)(b * 18 + o) * HWSZ + y * WW + x0 + ptile * 16 + l15] = acc[r] + offb[o];
  }
}

// ---------------------------------------------------------------------------
// Deformable conv im2col MFMA GEMM, c-major K (k = c*9 + n): all 9 taps of a
// channel consumed consecutively -> each row window read once (L1/L2 reuse).
// bf16 input planes; parity-baked 4-wide bilinear weights (aligned 8B loads).
// Layer-2 identity residual folded as 64 extra K columns.
// mode 0: out = bf16(relu(acc+cb)) -> h1 ;  mode 1: fp32 -> d_out
// ---------------------------------------------------------------------------
__global__ __launch_bounds__(512, 4) void deform_mfma_kernel(
    const unsigned short* __restrict__ in, const float* __restrict__ off,
    const short* __restrict__ wbf, const float* __restrict__ cbv,
    const unsigned short* __restrict__ xid, float* __restrict__ outf,
    unsigned short* __restrict__ outb, int cshift, int KCONV, int KTOT, int mode) {
  __shared__ f32x4 dwa[576];   // row-0 weights (parity-baked, w[3]=0)
  __shared__ f32x4 dwb[576];   // row-1 weights
  __shared__ int2 dij[576];    // element offsets of even-aligned windows
  __shared__ short wlds[128 * 40];
  __shared__ short vlds[64 * 40];
  const int tid = threadIdx.x;
  const int lane = tid & 63, wv = tid >> 6;
  const int pb = ((blockIdx.x & 7) << 6) | (blockIdx.x >> 3);  // XCD swizzle
  const int pix0 = pb << 6;
  const int x0 = pix0 & 127, y = (pix0 >> 7) & 127, b = pix0 >> 14;
  const int Cin = 1 << cshift;
  const unsigned short* inb = in + (size_t)b * Cin * HWSZ;
  const int p = lane, kb = wv;
  const int l15 = lane & 15, quad = lane >> 4;
  const int ptile = wv & 3, ohalf = wv >> 2;

  // ---- bilinear descriptors: 9 kernel points x 64 pixels ----
  for (int t = tid; t < 576; t += 512) {
    int n = t >> 6, pp = t & 63;
    float offy = off[(size_t)(b * 18 + n) * HWSZ + y * WW + x0 + pp];
    float offx = off[(size_t)(b * 18 + 9 + n) * HWSZ + y * WW + x0 + pp];
    float py = offy + (float)(n / 3 - 1) + (float)(y + 1);
    float px = offx + (float)(n % 3 - 1) + (float)(x0 + pp + 1);
    py = fminf(fmaxf(py, 0.f), 129.f);
    px = fminf(fmaxf(px, 0.f), 129.f);
    float fy = floorf(py), fx = floorf(px);
    float qy1 = fminf(fy + 1.f, 129.f), qx1 = fminf(fx + 1.f, 129.f);
    float ty0 = 1.f + fy - py, ty1 = 1.f - (qy1 - py);
    float tx0 = 1.f + fx - px, tx1 = 1.f - (qx1 - px);
    int iy0 = (int)fy - 1, ix0 = (int)fx - 1;
    int iy1 = (int)qy1 - 1, ix1 = (int)qx1 - 1;
    if ((unsigned)iy0 >= (unsigned)HH) ty0 = 0.f;   // pad row -> weight 0
    if ((unsigned)iy1 >= (unsigned)HH) ty1 = 0.f;
    bool vx0 = (unsigned)ix0 < (unsigned)WW, vx1 = (unsigned)ix1 < (unsigned)WW;
    int bx = min(max(ix0, 0), WW - 2);
    float wxA = (((ix0 == bx) && vx0) ? tx0 : 0.f) + (((ix1 == bx) && vx1) ? tx1 : 0.f);
    float wxB = (((ix0 == bx + 1) && vx0) ? tx0 : 0.f) + (((ix1 == bx + 1) && vx1) ? tx1 : 0.f);
    int bxe = bx & ~1, sel = bx & 1;
    f32x4 wa, wb;
    wa[0] = sel ? 0.f : ty0 * wxA; wa[1] = sel ? ty0 * wxA : ty0 * wxB;
    wa[2] = sel ? ty0 * wxB : 0.f; wa[3] = 0.f;
    wb[0] = sel ? 0.f : ty1 * wxA; wb[1] = sel ? ty1 * wxA : ty1 * wxB;
    wb[2] = sel ? ty1 * wxB : 0.f; wb[3] = 0.f;
    dwa[t] = wa; dwb[t] = wb;
    int by0 = min(max(iy0, 0), HH - 1), by1 = min(max(iy1, 0), HH - 1);
    dij[t] = make_int2(by0 * WW + bxe, by1 * WW + bxe);
  }

  f32x4 acc[4];
#pragma unroll
  for (int i = 0; i < 4; i++) acc[i] = (f32x4){0.f, 0.f, 0.f, 0.f};
  __syncthreads();

  for (int k0 = 0; k0 < KTOT; k0 += 32) {
    s16x8 wreg = *(const s16x8*)&wbf[(size_t)(tid >> 2) * KTOT + k0 + (tid & 3) * 8];
    s16x4 pk;
#pragma unroll
    for (int i = 0; i < 4; i++) {
      int k = k0 + kb * 4 + i;          // wave-uniform
      if (k < KCONV) {
        int c = k / 9;
        int n = k - c * 9;
        int d = n * 64 + p;
        f32x4 wa = dwa[d], wb = dwb[d];
        int2 ij = dij[d];
        const unsigned short* pl = inb + (size_t)c * HWSZ;
        US4 a = *(const US4*)(pl + ij.x);
        US4 c2 = *(const US4*)(pl + ij.y);
        float s = wa[0] * b2f(a.u[0]) + wa[1] * b2f(a.u[1]) + wa[2] * b2f(a.u[2])
                + wb[0] * b2f(c2.u[0]) + wb[1] * b2f(c2.u[1]) + wb[2] * b2f(c2.u[2]);
        pk[i] = tobf(s);
      } else {
        int c = k - KCONV;
        pk[i] = (short)xid[((size_t)b * 64 + c) * HWSZ + y * WW + x0 + p];
      }
    }
    __syncthreads();
    *(s16x8*)&wlds[(tid >> 2) * 40 + (tid & 3) * 8] = wreg;
    *(s16x4*)&vlds[p * 40 + kb * 4] = pk;
    __syncthreads();
    bf16x8 bfr = *(const bf16x8*)&vlds[(ptile * 16 + l15) * 40 + quad * 8];
#pragma unroll
    for (int ot = 0; ot < 4; ot++) {
      bf16x8 afr = *(const bf16x8*)&wlds[(ohalf * 64 + ot * 16 + l15) * 40 + quad * 8];
      acc[ot] = __builtin_amdgcn_mfma_f32_16x16x32_bf16(afr, bfr, acc[ot], 0, 0, 0);
    }
    __syncthreads();
  }

  // epilogue: + folded BN shift (+ folded residual consts), ReLU
  int px_ = x0 + ptile * 16 + l15;
#pragma unroll
  for (int ot = 0; ot < 4; ot++) {
#pragma unroll
    for (int r = 0; r < 4; r++) {
      int o = ohalf * 64 + ot * 16 + quad * 4 + r;
      float v = fmaxf(acc[ot][r] + cbv[o], 0.f);
      size_t gidx = (size_t)(b * COUT + o) * HWSZ + y * WW + px_;
      if (mode == 0) outb[gidx] = (unsigned short)tobf(v);
      else outf[gidx] = v;
    }
  }
}

// ---------------------------------------------------------------------------
extern "C" void kernel_launch(void* const* d_in, const int* in_sizes, int n_in,
                              void* d_out, int out_size, void* d_ws, size_t ws_size,
                              hipStream_t stream) {
  const float* x        = (const float*)d_in[0];
  const float* dc1_offw = (const float*)d_in[1];
  const float* dc1_offb = (const float*)d_in[2];
  const float* dc1_w    = (const float*)d_in[3];
  const float* bn1_g    = (const float*)d_in[4];
  const float* bn1_b    = (const float*)d_in[5];
  const float* bn1_m    = (const float*)d_in[6];
  const float* bn1_v    = (const float*)d_in[7];
  const float* dc2_offw = (const float*)d_in[8];
  const float* dc2_offb = (const float*)d_in[9];
  const float* dc2_w    = (const float*)d_in[10];
  const float* bn2_g    = (const float*)d_in[11];
  const float* bn2_b    = (const float*)d_in[12];
  const float* bn2_m    = (const float*)d_in[13];
  const float* bn2_v    = (const float*)d_in[14];
  const float* id_w     = (const float*)d_in[15];
  const float* id_b     = (const float*)d_in[16];
  const float* bn3_g    = (const float*)d_in[17];
  const float* bn3_b    = (const float*)d_in[18];
  const float* bn3_m    = (const float*)d_in[19];
  const float* bn3_v    = (const float*)d_in[20];

  float* wsf = (float*)d_ws;
  float* off1 = wsf;                                   // 2*18*16384 f
  float* off2 = off1 + (size_t)BB * 18 * HWSZ;
  float* cb1  = off2 + (size_t)BB * 18 * HWSZ;
  float* cb2  = cb1 + 128;
  unsigned short* xbf = (unsigned short*)(cb2 + 128);  // 2*64*16384 bf16
  unsigned short* h1  = xbf + (size_t)BB * 64 * HWSZ;  // 2*128*16384 bf16
  short* wbf1  = (short*)(h1 + (size_t)BB * COUT * HWSZ);  // 128 x 576
  short* wbf2  = wbf1 + (size_t)128 * 576;             // 128 x 1216
  short* woff1 = wbf2 + (size_t)128 * 1216;            // 32 x 576
  short* woff2 = woff1 + (size_t)32 * 576;             // 32 x 1152

  const int K1 = 576, K2 = 1152, KT2 = 1216;

  // --- prep ---
  hipLaunchKernelGGL(prep_scale_kernel, dim3((K1 + 255) / 256, 128), dim3(256), 0, stream,
                     dc1_w, bn1_g, bn1_v, wbf1, K1, K1, 0);
  hipLaunchKernelGGL(prep_scale_kernel, dim3((K2 + 255) / 256, 128), dim3(256), 0, stream,
                     dc2_w, bn2_g, bn2_v, wbf2, K2, KT2, 0);
  hipLaunchKernelGGL(prep_scale_kernel, dim3(1, 128), dim3(256), 0, stream,
                     id_w, bn3_g, bn3_v, wbf2, 64, KT2, K2);
  hipLaunchKernelGGL(prep_off_kernel, dim3((K1 + 255) / 256, 32), dim3(256), 0, stream,
                     dc1_offw, woff1, K1, 64);
  hipLaunchKernelGGL(prep_off_kernel, dim3((K2 + 255) / 256, 32), dim3(256), 0, stream,
                     dc2_offw, woff2, K2, 128);
  hipLaunchKernelGGL(prep_bias_kernel, dim3(1), dim3(128), 0, stream,
                     bn1_b, bn1_m, bn1_g, bn1_v, bn2_b, bn2_m, bn2_g, bn2_v,
                     bn3_b, bn3_m, bn3_g, bn3_v, id_b, cb1, cb2);
  hipLaunchKernelGGL(xcast_kernel, dim3(2048), dim3(256), 0, stream,
                     x, xbf, BB * 64 * HWSZ / 4);

  // --- layer 1 ---
  hipLaunchKernelGGL(offconv_mfma_kernel, dim3(512), dim3(512), 0, stream,
                     xbf, woff1, dc1_offb, off1, 6);
  hipLaunchKernelGGL(deform_mfma_kernel, dim3(512), dim3(512), 0, stream,
                     xbf, off1, wbf1, cb1, (const unsigned short*)nullptr,
                     (float*)nullptr, h1, 6, K1, K1, 0);
  // --- layer 2 (identity residual folded into GEMM) ---
  hipLaunchKernelGGL(offconv_mfma_kernel, dim3(512), dim3(512), 0, stream,
                     h1, woff2, dc2_offb, off2, 7);
  hipLaunchKernelGGL(deform_mfma_kernel, dim3(512), dim3(512), 0, stream,
                     h1, off2, wbf2, cb2, xbf, (float*)d_out,
                     (unsigned short*)nullptr, 7, K2, KT2, 1);
}

// Round 4
// 210.503 us; speedup vs baseline: 1.5424x; 1.5424x over previous
//
#include <hip/hip_runtime.h>
#include <math.h>

#define HH 128
#define WW 128
#define HWSZ (HH * WW)
#define BB 2
#define COUT 128

typedef __bf16 bf16x8 __attribute__((ext_vector_type(8)));
typedef float f32x4 __attribute__((ext_vector_type(4)));
typedef short s16x8 __attribute__((ext_vector_type(8)));
typedef short s16x4 __attribute__((ext_vector_type(4)));
typedef unsigned short u16x4 __attribute__((ext_vector_type(4)));
typedef unsigned short u16x8 __attribute__((ext_vector_type(8)));

__device__ __forceinline__ short tobf(float f) {
  union { float f; unsigned u; } v; v.f = f;
  unsigned r = v.u + 0x7fffu + ((v.u >> 16) & 1u);  // RNE
  return (short)(r >> 16);
}
__device__ __forceinline__ float asf(unsigned u) {
  union { unsigned u; float f; } v; v.u = u;
  return v.f;
}

// ---------------------------------------------------------------------------
// Weight prep: dst[o*dstStride + dstOff + col] = bf16(src[o*K+k] * inv[o])
// col = remapCin ? (k%9)*remapCin + (k/9) : k   (n-major K for NHWC chunks)
// ---------------------------------------------------------------------------
__global__ __launch_bounds__(256) void prep_scale_kernel(
    const float* __restrict__ src, const float* __restrict__ g,
    const float* __restrict__ v, short* __restrict__ dst,
    int K, int dstStride, int dstOff, int remapCin) {
  int k = blockIdx.x * 256 + threadIdx.x;
  int o = blockIdx.y;
  if (k >= K) return;
  float inv = g[o] / sqrtf(v[o] + 1e-5f);
  int col = remapCin ? (k % 9) * remapCin + (k / 9) : k;
  dst[(size_t)o * dstStride + dstOff + col] = tobf(src[(size_t)o * K + k] * inv);
}

// Offset-conv weights: n-major remap, M padded to 32
__global__ __launch_bounds__(256) void prep_off_kernel(const float* __restrict__ src,
                                                       short* __restrict__ dst,
                                                       int K, int Cin) {
  int k = blockIdx.x * 256 + threadIdx.x;
  int o = blockIdx.y;  // 0..31
  if (k >= K) return;
  int col = (k % 9) * Cin + (k / 9);
  dst[(size_t)o * K + col] = (o < 18) ? tobf(src[(size_t)o * K + k]) : (short)0;
}

// Epilogue constants: cb1 = beta1; cb2 = beta2 + id_b*inv3 + beta3
__global__ __launch_bounds__(128) void prep_bias_kernel(
    const float* b1, const float* m1, const float* g1, const float* v1,
    const float* b2, const float* m2, const float* g2, const float* v2,
    const float* b3, const float* m3, const float* g3, const float* v3,
    const float* idb, float* cb1, float* cb2) {
  int o = threadIdx.x;
  float inv1 = g1[o] / sqrtf(v1[o] + 1e-5f);
  float inv2 = g2[o] / sqrtf(v2[o] + 1e-5f);
  float inv3 = g3[o] / sqrtf(v3[o] + 1e-5f);
  cb1[o] = b1[o] - m1[o] * inv1;
  cb2[o] = (b2[o] - m2[o] * inv2) + idb[o] * inv3 + (b3[o] - m3[o] * inv3);
}

// ---------------------------------------------------------------------------
// x (B,64,H,W) fp32 NCHW  ->  xnhwc (B,H,W,64) bf16. LDS transpose per 64 px.
// ---------------------------------------------------------------------------
__global__ __launch_bounds__(256) void xcast_kernel(const float* __restrict__ x,
                                                    unsigned short* __restrict__ xn) {
  __shared__ short lds[64 * 72];  // [p][c] pad 8
  int tid = threadIdx.x;
  int gp0 = blockIdx.x * 64;          // global pixel base (b*HWSZ + y*WW + x)
  int b = gp0 >> 14;
  int pl0 = gp0 & 16383;
  int p = tid & 63;
  int cb = (tid >> 6) * 16;
#pragma unroll
  for (int i = 0; i < 16; i++) {
    int c = cb + i;
    float v = x[((size_t)(b * 64 + c)) * HWSZ + pl0 + p];
    lds[p * 72 + c] = tobf(v);
  }
  __syncthreads();
  int pw = tid >> 2, cseg = (tid & 3) * 16;
  u16x8 a = *(const u16x8*)&lds[pw * 72 + cseg];
  u16x8 b8 = *(const u16x8*)&lds[pw * 72 + cseg + 8];
  *(u16x8*)&xn[(size_t)(gp0 + pw) * 64 + cseg] = a;
  *(u16x8*)&xn[(size_t)(gp0 + pw) * 64 + cseg + 8] = b8;
}

// ---------------------------------------------------------------------------
// Offset conv as MFMA GEMM on NHWC bf16 input. Block: 64 px x 32 M, 512 thr.
// K n-major: per 32-chunk tap position n uniform, channels contiguous.
// ---------------------------------------------------------------------------
__global__ __launch_bounds__(512, 4) void offconv_mfma_kernel(
    const unsigned short* __restrict__ in, const short* __restrict__ woff,
    const float* __restrict__ offb, float* __restrict__ off, int cshift) {
  __shared__ short wlds[32 * 40];
  __shared__ short vlds[64 * 40];
  const int tid = threadIdx.x;
  const int lane = tid & 63;
  const int wv = tid >> 6;
  const int pb = ((blockIdx.x & 7) << 6) | (blockIdx.x >> 3);  // XCD swizzle
  const int pix0 = pb << 6;
  const int x0 = pix0 & 127, y = (pix0 >> 7) & 127, b = pix0 >> 14;
  const int Cin = 1 << cshift;
  const int Kc = 9 << cshift;
  const unsigned short* inb = in + (size_t)b * HWSZ * Cin;
  const int ps = tid >> 3, cq = tid & 7;   // sampling coords
  const int l15 = lane & 15, quad = lane >> 4;
  const int ptile = wv & 3, otile = wv >> 2;

  f32x4 acc = {0.f, 0.f, 0.f, 0.f};

  for (int k0 = 0; k0 < Kc; k0 += 32) {
    s16x8 wreg;
    if (tid < 128) wreg = *(const s16x8*)&woff[(size_t)(tid >> 2) * Kc + k0 + (tid & 3) * 8];
    int n = k0 >> cshift;
    int dy = n / 3 - 1, dx = n % 3 - 1;
    int yy = y + dy;
    int xx = x0 + ps + dx;
    int c0 = (k0 & (Cin - 1)) + cq * 4;
    u16x4 pk = {0, 0, 0, 0};
    if (((unsigned)yy < (unsigned)HH) && ((unsigned)xx < (unsigned)WW))
      pk = *(const u16x4*)&inb[((size_t)yy * WW + xx) * Cin + c0];
    __syncthreads();
    if (tid < 128) *(s16x8*)&wlds[(tid >> 2) * 40 + (tid & 3) * 8] = wreg;
    *(u16x4*)&vlds[ps * 40 + cq * 4] = pk;
    __syncthreads();
    bf16x8 bfr = *(const bf16x8*)&vlds[(ptile * 16 + l15) * 40 + quad * 8];
    bf16x8 afr = *(const bf16x8*)&wlds[(otile * 16 + l15) * 40 + quad * 8];
    acc = __builtin_amdgcn_mfma_f32_16x16x32_bf16(afr, bfr, acc, 0, 0, 0);
  }
#pragma unroll
  for (int r = 0; r < 4; r++) {
    int o = otile * 16 + quad * 4 + r;
    if (o < 18)
      off[(size_t)(b * 18 + o) * HWSZ + y * WW + x0 + ptile * 16 + l15] = acc[r] + offb[o];
  }
}

// ---------------------------------------------------------------------------
// Deformable conv im2col MFMA GEMM on NHWC bf16 activations.
// K n-major (k = n*Cin + c): per chunk n uniform -> descriptor broadcast,
// 4 coalesced channel-contiguous tap loads per thread (8 lanes x 8B = 64B).
// Layer-2 identity residual folded as 64 extra K columns (xid NHWC).
// mode 0: h1 NHWC bf16 (LDS-transposed epilogue); mode 1: d_out NCHW fp32.
// ---------------------------------------------------------------------------
__global__ __launch_bounds__(512, 4) void deform_mfma_kernel(
    const unsigned short* __restrict__ in, const float* __restrict__ off,
    const short* __restrict__ wbf, const float* __restrict__ cbv,
    const unsigned short* __restrict__ xid, float* __restrict__ outf,
    unsigned short* __restrict__ outb, int cshift, int KCONV, int KTOT, int mode) {
  __shared__ __align__(16) char smem[33792];
  float4* dw = (float4*)smem;                    // [576] tap weights
  int4* da = (int4*)(smem + 9216);               // [576] {a00, dxC, dyC, -}
  short* wlds = (short*)(smem + 18432);          // 128 x 40
  short* vlds = (short*)(smem + 28672);          // 64 x 40
  short* trans = (short*)smem;                   // 64 x 136 (overlays desc)

  const int tid = threadIdx.x;
  const int lane = tid & 63;
  const int wv = tid >> 6;
  const int pb = ((blockIdx.x & 7) << 6) | (blockIdx.x >> 3);  // XCD swizzle
  const int pix0 = pb << 6;
  const int x0 = pix0 & 127, y = (pix0 >> 7) & 127, b = pix0 >> 14;
  const int Cin = 1 << cshift;
  const unsigned short* inb = in + (size_t)b * HWSZ * Cin;
  const int ps = tid >> 3, cq = tid & 7;
  const int l15 = lane & 15, quad = lane >> 4;
  const int ptile = wv & 3, ohalf = wv >> 2;

  // ---- bilinear descriptors: 9 kernel points x 64 pixels ----
  for (int t = tid; t < 576; t += 512) {
    int n = t >> 6, pp = t & 63;
    float offy = off[(size_t)(b * 18 + n) * HWSZ + y * WW + x0 + pp];
    float offx = off[(size_t)(b * 18 + 9 + n) * HWSZ + y * WW + x0 + pp];
    float py = offy + (float)(n / 3 - 1) + (float)(y + 1);
    float px = offx + (float)(n % 3 - 1) + (float)(x0 + pp + 1);
    py = fminf(fmaxf(py, 0.f), 129.f);
    px = fminf(fmaxf(px, 0.f), 129.f);
    float fy = floorf(py), fx = floorf(px);
    float qy1 = fminf(fy + 1.f, 129.f), qx1 = fminf(fx + 1.f, 129.f);
    float ty0 = 1.f + fy - py, ty1 = 1.f - (qy1 - py);
    float tx0 = 1.f + fx - px, tx1 = 1.f - (qx1 - px);
    int iy0 = (int)fy - 1, ix0 = (int)fx - 1;
    int iy1 = (int)qy1 - 1, ix1 = (int)qx1 - 1;
    if ((unsigned)iy0 >= (unsigned)HH) ty0 = 0.f;   // pad -> weight 0
    if ((unsigned)iy1 >= (unsigned)HH) ty1 = 0.f;
    if ((unsigned)ix0 >= (unsigned)WW) tx0 = 0.f;
    if ((unsigned)ix1 >= (unsigned)WW) tx1 = 0.f;
    int by0 = min(max(iy0, 0), HH - 1), by1 = min(max(iy1, 0), HH - 1);
    int bx0 = min(max(ix0, 0), WW - 1), bx1 = min(max(ix1, 0), WW - 1);
    dw[t] = make_float4(ty0 * tx0, ty0 * tx1, ty1 * tx0, ty1 * tx1);
    da[t] = make_int4((by0 * WW + bx0) * Cin, (bx1 - bx0) * Cin,
                      (by1 - by0) * WW * Cin, 0);
  }

  f32x4 acc[4];
#pragma unroll
  for (int i = 0; i < 4; i++) acc[i] = (f32x4){0.f, 0.f, 0.f, 0.f};
  __syncthreads();

  for (int k0 = 0; k0 < KTOT; k0 += 32) {
    s16x8 wreg = *(const s16x8*)&wbf[(size_t)(tid >> 2) * KTOT + k0 + (tid & 3) * 8];
    u16x4 pk;
    if (k0 < KCONV) {
      int n = k0 >> cshift;
      int c0 = (k0 & (Cin - 1)) + cq * 4;
      int d = n * 64 + ps;
      float4 w = dw[d];
      int4 a = da[d];
      const unsigned short* ptr = inb + a.x + c0;
      uint2 t00 = *(const uint2*)(ptr);
      uint2 t01 = *(const uint2*)(ptr + a.y);
      uint2 t10 = *(const uint2*)(ptr + a.z);
      uint2 t11 = *(const uint2*)(ptr + a.y + a.z);
      float v0 = w.x * asf(t00.x << 16) + w.y * asf(t01.x << 16)
               + w.z * asf(t10.x << 16) + w.w * asf(t11.x << 16);
      float v1 = w.x * asf(t00.x & 0xffff0000u) + w.y * asf(t01.x & 0xffff0000u)
               + w.z * asf(t10.x & 0xffff0000u) + w.w * asf(t11.x & 0xffff0000u);
      float v2 = w.x * asf(t00.y << 16) + w.y * asf(t01.y << 16)
               + w.z * asf(t10.y << 16) + w.w * asf(t11.y << 16);
      float v3 = w.x * asf(t00.y & 0xffff0000u) + w.y * asf(t01.y & 0xffff0000u)
               + w.z * asf(t10.y & 0xffff0000u) + w.w * asf(t11.y & 0xffff0000u);
      pk[0] = (unsigned short)tobf(v0);
      pk[1] = (unsigned short)tobf(v1);
      pk[2] = (unsigned short)tobf(v2);
      pk[3] = (unsigned short)tobf(v3);
    } else {  // identity-residual columns: v = x (NHWC) directly
      int c = k0 - KCONV + cq * 4;
      pk = *(const u16x4*)&xid[((size_t)(b * HWSZ) + y * WW + x0 + ps) * 64 + c];
    }
    __syncthreads();
    *(s16x8*)&wlds[(tid >> 2) * 40 + (tid & 3) * 8] = wreg;
    *(u16x4*)&vlds[ps * 40 + cq * 4] = pk;
    __syncthreads();
    bf16x8 bfr = *(const bf16x8*)&vlds[(ptile * 16 + l15) * 40 + quad * 8];
#pragma unroll
    for (int ot = 0; ot < 4; ot++) {
      bf16x8 afr = *(const bf16x8*)&wlds[(ohalf * 64 + ot * 16 + l15) * 40 + quad * 8];
      acc[ot] = __builtin_amdgcn_mfma_f32_16x16x32_bf16(afr, bfr, acc[ot], 0, 0, 0);
    }
    __syncthreads();
  }

  if (mode == 1) {
    // d_out NCHW fp32
    int px_ = x0 + ptile * 16 + l15;
#pragma unroll
    for (int ot = 0; ot < 4; ot++) {
#pragma unroll
      for (int r = 0; r < 4; r++) {
        int o = ohalf * 64 + ot * 16 + quad * 4 + r;
        float v = fmaxf(acc[ot][r] + cbv[o], 0.f);
        outf[(size_t)(b * COUT + o) * HWSZ + y * WW + px_] = v;
      }
    }
  } else {
    // h1 NHWC bf16 via LDS transpose (trans overlays dead descriptor region)
    int pl = ptile * 16 + l15;
#pragma unroll
    for (int ot = 0; ot < 4; ot++) {
      s16x4 t4;
#pragma unroll
      for (int r = 0; r < 4; r++) {
        int o = ohalf * 64 + ot * 16 + quad * 4 + r;
        t4[r] = tobf(fmaxf(acc[ot][r] + cbv[o], 0.f));
      }
      *(s16x4*)&trans[pl * 136 + ohalf * 64 + ot * 16 + quad * 4] = t4;
    }
    __syncthreads();
    int pw = tid >> 3, cseg = (tid & 7) * 16;
    u16x8 a = *(const u16x8*)&trans[pw * 136 + cseg];
    u16x8 b8 = *(const u16x8*)&trans[pw * 136 + cseg + 8];
    size_t gb = ((size_t)(b * HWSZ) + y * WW + x0 + pw) * 128 + cseg;
    *(u16x8*)&outb[gb] = a;
    *(u16x8*)&outb[gb + 8] = b8;
  }
}

// ---------------------------------------------------------------------------
extern "C" void kernel_launch(void* const* d_in, const int* in_sizes, int n_in,
                              void* d_out, int out_size, void* d_ws, size_t ws_size,
                              hipStream_t stream) {
  const float* x        = (const float*)d_in[0];
  const float* dc1_offw = (const float*)d_in[1];
  const float* dc1_offb = (const float*)d_in[2];
  const float* dc1_w    = (const float*)d_in[3];
  const float* bn1_g    = (const float*)d_in[4];
  const float* bn1_b    = (const float*)d_in[5];
  const float* bn1_m    = (const float*)d_in[6];
  const float* bn1_v    = (const float*)d_in[7];
  const float* dc2_offw = (const float*)d_in[8];
  const float* dc2_offb = (const float*)d_in[9];
  const float* dc2_w    = (const float*)d_in[10];
  const float* bn2_g    = (const float*)d_in[11];
  const float* bn2_b    = (const float*)d_in[12];
  const float* bn2_m    = (const float*)d_in[13];
  const float* bn2_v    = (const float*)d_in[14];
  const float* id_w     = (const float*)d_in[15];
  const float* id_b     = (const float*)d_in[16];
  const float* bn3_g    = (const float*)d_in[17];
  const float* bn3_b    = (const float*)d_in[18];
  const float* bn3_m    = (const float*)d_in[19];
  const float* bn3_v    = (const float*)d_in[20];

  float* wsf = (float*)d_ws;
  float* off1 = wsf;                                   // 2*18*16384 f
  float* off2 = off1 + (size_t)BB * 18 * HWSZ;
  float* cb1  = off2 + (size_t)BB * 18 * HWSZ;
  float* cb2  = cb1 + 128;
  unsigned short* xbf = (unsigned short*)(cb2 + 128);  // NHWC (B,H,W,64)
  unsigned short* h1  = xbf + (size_t)BB * HWSZ * 64;  // NHWC (B,H,W,128)
  short* wbf1  = (short*)(h1 + (size_t)BB * HWSZ * COUT);  // 128 x 576
  short* wbf2  = wbf1 + (size_t)128 * 576;             // 128 x 1216
  short* woff1 = wbf2 + (size_t)128 * 1216;            // 32 x 576
  short* woff2 = woff1 + (size_t)32 * 576;             // 32 x 1152

  const int K1 = 576, K2 = 1152, KT2 = 1216;

  // --- prep ---
  hipLaunchKernelGGL(prep_scale_kernel, dim3((K1 + 255) / 256, 128), dim3(256), 0, stream,
                     dc1_w, bn1_g, bn1_v, wbf1, K1, K1, 0, 64);
  hipLaunchKernelGGL(prep_scale_kernel, dim3((K2 + 255) / 256, 128), dim3(256), 0, stream,
                     dc2_w, bn2_g, bn2_v, wbf2, K2, KT2, 0, 128);
  hipLaunchKernelGGL(prep_scale_kernel, dim3(1, 128), dim3(256), 0, stream,
                     id_w, bn3_g, bn3_v, wbf2, 64, KT2, K2, 0);
  hipLaunchKernelGGL(prep_off_kernel, dim3((K1 + 255) / 256, 32), dim3(256), 0, stream,
                     dc1_offw, woff1, K1, 64);
  hipLaunchKernelGGL(prep_off_kernel, dim3((K2 + 255) / 256, 32), dim3(256), 0, stream,
                     dc2_offw, woff2, K2, 128);
  hipLaunchKernelGGL(prep_bias_kernel, dim3(1), dim3(128), 0, stream,
                     bn1_b, bn1_m, bn1_g, bn1_v, bn2_b, bn2_m, bn2_g, bn2_v,
                     bn3_b, bn3_m, bn3_g, bn3_v, id_b, cb1, cb2);
  hipLaunchKernelGGL(xcast_kernel, dim3(BB * HWSZ / 64), dim3(256), 0, stream, x, xbf);

  // --- layer 1 ---
  hipLaunchKernelGGL(offconv_mfma_kernel, dim3(512), dim3(512), 0, stream,
                     xbf, woff1, dc1_offb, off1, 6);
  hipLaunchKernelGGL(deform_mfma_kernel, dim3(512), dim3(512), 0, stream,
                     xbf, off1, wbf1, cb1, (const unsigned short*)nullptr,
                     (float*)nullptr, h1, 6, K1, K1, 0);
  // --- layer 2 (identity residual folded into GEMM) ---
  hipLaunchKernelGGL(offconv_mfma_kernel, dim3(512), dim3(512), 0, stream,
                     h1, woff2, dc2_offb, off2, 7);
  hipLaunchKernelGGL(deform_mfma_kernel, dim3(512), dim3(512), 0, stream,
                     h1, off2, wbf2, cb2, xbf, (float*)d_out,
                     (unsigned short*)nullptr, 7, K2, KT2, 1);
}

// Round 5
// 195.738 us; speedup vs baseline: 1.6587x; 1.0754x over previous
//
#include <hip/hip_runtime.h>
#include <math.h>

#define HH 128
#define WW 128
#define HWSZ (HH * WW)
#define BB 2
#define COUT 128

typedef __bf16 bf16x8 __attribute__((ext_vector_type(8)));
typedef float f32x4 __attribute__((ext_vector_type(4)));
typedef float f32x2 __attribute__((ext_vector_type(2)));
typedef short s16x8 __attribute__((ext_vector_type(8)));
typedef short s16x4 __attribute__((ext_vector_type(4)));
typedef unsigned short u16x4 __attribute__((ext_vector_type(4)));
typedef unsigned short u16x8 __attribute__((ext_vector_type(8)));

__device__ __forceinline__ short tobf(float f) {
  union { float f; unsigned u; } v; v.f = f;
  unsigned r = v.u + 0x7fffu + ((v.u >> 16) & 1u);  // RNE
  return (short)(r >> 16);
}
__device__ __forceinline__ float asf(unsigned u) {
  union { unsigned u; float f; } v; v.u = u;
  return v.f;
}
__device__ __forceinline__ f32x2 up2(unsigned u) {   // 2 bf16 -> 2 f32
  f32x2 r; r[0] = asf(u << 16); r[1] = asf(u & 0xffff0000u); return r;
}
__device__ __forceinline__ unsigned pack2bf(float a, float b) {
  union { float f; unsigned u; } x, y; x.f = a; y.f = b;
  unsigned lo = (x.u + 0x7fffu + ((x.u >> 16) & 1u)) >> 16;
  unsigned hi = (y.u + 0x7fffu + ((y.u >> 16) & 1u)) & 0xffff0000u;
  return lo | hi;
}

// ---------------------------------------------------------------------------
// Merged prep: all weight conversions/remaps + epilogue constants, 1 launch.
// Segments (flat index):
//  [0, A0)        wbf1: 128x576, dc1_w * inv1, remap Cin=64 (n-major)
//  [A0, A1)       wbf2 conv: 128x1152, dc2_w * inv2, remap Cin=128
//  [A1, A2)       wbf2 id: 128x64, id_w * inv3
//  [A2, A3)       woff1: 32x576 (o<18 from dc1_offw remap64, else 0)
//  [A3, A4)       woff2: 32x1152
//  [A4, A5)       cb1[128], cb2[128]
// ---------------------------------------------------------------------------
#define PA0 73728
#define PA1 221184
#define PA2 229376
#define PA3 247808
#define PA4 284672
#define PA5 284928
__global__ __launch_bounds__(256) void prep_all_kernel(
    const float* __restrict__ dc1_w, const float* __restrict__ dc2_w,
    const float* __restrict__ id_w, const float* __restrict__ dc1_offw,
    const float* __restrict__ dc2_offw,
    const float* g1, const float* b1, const float* m1, const float* v1,
    const float* g2, const float* b2, const float* m2, const float* v2,
    const float* g3, const float* b3, const float* m3, const float* v3,
    const float* idb,
    short* __restrict__ wbf1, short* __restrict__ wbf2,
    short* __restrict__ woff1, short* __restrict__ woff2,
    float* __restrict__ cb1, float* __restrict__ cb2) {
  int idx = blockIdx.x * 256 + threadIdx.x;
  if (idx < PA0) {
    int o = idx / 576, k = idx - o * 576;
    float inv = g1[o] / sqrtf(v1[o] + 1e-5f);
    int col = (k % 9) * 64 + k / 9;
    wbf1[o * 576 + col] = tobf(dc1_w[(size_t)o * 576 + k] * inv);
  } else if (idx < PA1) {
    int j = idx - PA0;
    int o = j / 1152, k = j - o * 1152;
    float inv = g2[o] / sqrtf(v2[o] + 1e-5f);
    int col = (k % 9) * 128 + k / 9;
    wbf2[o * 1216 + col] = tobf(dc2_w[(size_t)o * 1152 + k] * inv);
  } else if (idx < PA2) {
    int j = idx - PA1;
    int o = j >> 6, k = j & 63;
    float inv = g3[o] / sqrtf(v3[o] + 1e-5f);
    wbf2[o * 1216 + 1152 + k] = tobf(id_w[(size_t)o * 64 + k] * inv);
  } else if (idx < PA3) {
    int j = idx - PA2;
    int o = j / 576, k = j - o * 576;
    int col = (k % 9) * 64 + k / 9;
    woff1[o * 576 + col] = (o < 18) ? tobf(dc1_offw[(size_t)o * 576 + k]) : (short)0;
  } else if (idx < PA4) {
    int j = idx - PA3;
    int o = j / 1152, k = j - o * 1152;
    int col = (k % 9) * 128 + k / 9;
    woff2[o * 1152 + col] = (o < 18) ? tobf(dc2_offw[(size_t)o * 1152 + k]) : (short)0;
  } else if (idx < PA5) {
    int j = idx - PA4;
    if (j < 128) {
      float inv = g1[j] / sqrtf(v1[j] + 1e-5f);
      cb1[j] = b1[j] - m1[j] * inv;
    } else {
      int o = j - 128;
      float inv2_ = g2[o] / sqrtf(v2[o] + 1e-5f);
      float inv3_ = g3[o] / sqrtf(v3[o] + 1e-5f);
      cb2[o] = (b2[o] - m2[o] * inv2_) + idb[o] * inv3_ + (b3[o] - m3[o] * inv3_);
    }
  }
}

// ---------------------------------------------------------------------------
// x (B,64,H,W) fp32 NCHW  ->  xnhwc (B,H,W,64) bf16. LDS transpose per 64 px.
// ---------------------------------------------------------------------------
__global__ __launch_bounds__(256) void xcast_kernel(const float* __restrict__ x,
                                                    unsigned short* __restrict__ xn) {
  __shared__ short lds[64 * 72];
  int tid = threadIdx.x;
  int gp0 = blockIdx.x * 64;
  int b = gp0 >> 14;
  int pl0 = gp0 & 16383;
  int p = tid & 63;
  int cb = (tid >> 6) * 16;
#pragma unroll
  for (int i = 0; i < 16; i++) {
    int c = cb + i;
    lds[p * 72 + c] = tobf(x[((size_t)(b * 64 + c)) * HWSZ + pl0 + p]);
  }
  __syncthreads();
  int pw = tid >> 2, cseg = (tid & 3) * 16;
  u16x8 a = *(const u16x8*)&lds[pw * 72 + cseg];
  u16x8 b8 = *(const u16x8*)&lds[pw * 72 + cseg + 8];
  *(u16x8*)&xn[(size_t)(gp0 + pw) * 64 + cseg] = a;
  *(u16x8*)&xn[(size_t)(gp0 + pw) * 64 + cseg + 8] = b8;
}

// ---------------------------------------------------------------------------
// Offset conv MFMA GEMM, NHWC bf16 input. Block: 32 px x 32 M, 256 thr =
// 4 waves (tile 16x16 each). Double-buffered LDS, 1 barrier per chunk.
// Grid 1024 -> 4+ blocks/CU.
// ---------------------------------------------------------------------------
__global__ __launch_bounds__(256, 8) void offconv_mfma_kernel(
    const unsigned short* __restrict__ in, const short* __restrict__ woff,
    const float* __restrict__ offb, float* __restrict__ off, int cshift) {
  __shared__ short wlds[2][32 * 40];
  __shared__ short vlds[2][32 * 40];
  const int tid = threadIdx.x;
  const int lane = tid & 63, wv = tid >> 6;
  const int pb = ((blockIdx.x & 7) << 7) | (blockIdx.x >> 3);  // XCD swizzle
  const int pix0 = pb << 5;
  const int x0 = pix0 & 127, y = (pix0 >> 7) & 127, b = pix0 >> 14;
  const int Cin = 1 << cshift;
  const int Kc = 9 << cshift;
  const unsigned short* inb = in + (size_t)b * HWSZ * Cin;
  const int ps = tid >> 3, cq = tid & 7;
  const int l15 = lane & 15, quad = lane >> 4;
  const int ptile = wv & 1, otile = wv >> 1;

  s16x8 wreg;
  u16x4 pk;
  auto issue = [&](int k0) {
    if (tid < 128) wreg = *(const s16x8*)&woff[(size_t)(tid >> 2) * Kc + k0 + (tid & 3) * 8];
    int n = k0 >> cshift;
    int dy = n / 3 - 1, dx = n % 3 - 1;
    int yy = y + dy;
    int xx = x0 + ps + dx;
    int c0 = (k0 & (Cin - 1)) + cq * 4;
    pk = (u16x4){0, 0, 0, 0};
    if (((unsigned)yy < (unsigned)HH) && ((unsigned)xx < (unsigned)WW))
      pk = *(const u16x4*)&inb[((size_t)yy * WW + xx) * Cin + c0];
  };
  auto commit = [&](int buf) {
    if (tid < 128) *(s16x8*)&wlds[buf][(tid >> 2) * 40 + (tid & 3) * 8] = wreg;
    *(u16x4*)&vlds[buf][ps * 40 + cq * 4] = pk;
  };

  f32x4 acc = {0.f, 0.f, 0.f, 0.f};
  issue(0);
  commit(0);
  __syncthreads();
  const int NC = Kc >> 5;
  for (int ch = 0; ch < NC; ch++) {
    int cur = ch & 1;
    bool has = (ch + 1) < NC;
    if (has) issue((ch + 1) << 5);
    bf16x8 bfr = *(const bf16x8*)&vlds[cur][(ptile * 16 + l15) * 40 + quad * 8];
    bf16x8 afr = *(const bf16x8*)&wlds[cur][(otile * 16 + l15) * 40 + quad * 8];
    acc = __builtin_amdgcn_mfma_f32_16x16x32_bf16(afr, bfr, acc, 0, 0, 0);
    if (has) commit(cur ^ 1);
    __syncthreads();
  }
#pragma unroll
  for (int r = 0; r < 4; r++) {
    int o = otile * 16 + quad * 4 + r;
    if (o < 18)
      off[(size_t)(b * 18 + o) * HWSZ + y * WW + x0 + ptile * 16 + l15] = acc[r] + offb[o];
  }
}

// ---------------------------------------------------------------------------
// Deformable conv im2col MFMA GEMM, NHWC bf16, double-buffered LDS with a
// single barrier per 32-k chunk; packed-f32 bilinear blend (v_pk_fma_f32).
// Block: 64 px x 128 out, 512 thr = 8 waves (16px x 64out tiles, no overlap).
// mode 0: h1 NHWC bf16 (LDS-transposed epilogue); mode 1: d_out NCHW fp32.
// ---------------------------------------------------------------------------
__global__ __launch_bounds__(512, 4) void deform_mfma_kernel(
    const unsigned short* __restrict__ in, const float* __restrict__ off,
    const short* __restrict__ wbf, const float* __restrict__ cbv,
    const unsigned short* __restrict__ xid, float* __restrict__ outf,
    unsigned short* __restrict__ outb, int cshift, int KCONV, int KTOT, int mode) {
  __shared__ __align__(16) char smem[49152];
  float4* dw = (float4*)smem;                    // [576] tap weights
  int4* da = (int4*)(smem + 9216);               // [576] {base, dxC, dyC, -}
  short* wlds = (short*)(smem + 18432);          // 2 x 128x40
  short* vlds = (short*)(smem + 38912);          // 2 x 64x40
  short* trans = (short*)smem;                   // 64 x 136 (overlays desc)

  const int tid = threadIdx.x;
  const int lane = tid & 63, wv = tid >> 6;
  const int pb = ((blockIdx.x & 7) << 6) | (blockIdx.x >> 3);  // XCD swizzle
  const int pix0 = pb << 6;
  const int x0 = pix0 & 127, y = (pix0 >> 7) & 127, b = pix0 >> 14;
  const int Cin = 1 << cshift;
  const unsigned short* inb = in + (size_t)b * HWSZ * Cin;
  const int ps = tid >> 3, cq = tid & 7;
  const int l15 = lane & 15, quad = lane >> 4;
  const int ptile = wv & 3, og = wv >> 2;

  // ---- bilinear descriptors: 9 kernel points x 64 pixels ----
  for (int t = tid; t < 576; t += 512) {
    int n = t >> 6, pp = t & 63;
    float offy = off[(size_t)(b * 18 + n) * HWSZ + y * WW + x0 + pp];
    float offx = off[(size_t)(b * 18 + 9 + n) * HWSZ + y * WW + x0 + pp];
    float py = offy + (float)(n / 3 - 1) + (float)(y + 1);
    float px = offx + (float)(n % 3 - 1) + (float)(x0 + pp + 1);
    py = fminf(fmaxf(py, 0.f), 129.f);
    px = fminf(fmaxf(px, 0.f), 129.f);
    float fy = floorf(py), fx = floorf(px);
    float qy1 = fminf(fy + 1.f, 129.f), qx1 = fminf(fx + 1.f, 129.f);
    float ty0 = 1.f + fy - py, ty1 = 1.f - (qy1 - py);
    float tx0 = 1.f + fx - px, tx1 = 1.f - (qx1 - px);
    int iy0 = (int)fy - 1, ix0 = (int)fx - 1;
    int iy1 = (int)qy1 - 1, ix1 = (int)qx1 - 1;
    if ((unsigned)iy0 >= (unsigned)HH) ty0 = 0.f;   // pad -> weight 0
    if ((unsigned)iy1 >= (unsigned)HH) ty1 = 0.f;
    if ((unsigned)ix0 >= (unsigned)WW) tx0 = 0.f;
    if ((unsigned)ix1 >= (unsigned)WW) tx1 = 0.f;
    int by0 = min(max(iy0, 0), HH - 1), by1 = min(max(iy1, 0), HH - 1);
    int bx0 = min(max(ix0, 0), WW - 1), bx1 = min(max(ix1, 0), WW - 1);
    dw[t] = make_float4(ty0 * tx0, ty0 * tx1, ty1 * tx0, ty1 * tx1);
    da[t] = make_int4((by0 * WW + bx0) * Cin, (bx1 - bx0) * Cin,
                      (by1 - by0) * WW * Cin, 0);
  }

  f32x4 acc[4];
#pragma unroll
  for (int i = 0; i < 4; i++) acc[i] = (f32x4){0.f, 0.f, 0.f, 0.f};

  // pipeline registers
  s16x8 wreg;
  uint2 t00, t01, t10, t11, pkr;
  float4 wgt;
  int isres = 0;

  auto issue = [&](int k0) {
    wreg = *(const s16x8*)&wbf[(size_t)(tid >> 2) * KTOT + k0 + (tid & 3) * 8];
    if (k0 < KCONV) {
      isres = 0;
      int n = k0 >> cshift;
      int c0 = (k0 & (Cin - 1)) + cq * 4;
      int d = (n << 6) + ps;
      wgt = dw[d];
      int4 a = da[d];
      const unsigned short* ptr = inb + a.x + c0;
      t00 = *(const uint2*)(ptr);
      t01 = *(const uint2*)(ptr + a.y);
      t10 = *(const uint2*)(ptr + a.z);
      t11 = *(const uint2*)(ptr + a.y + a.z);
    } else {
      isres = 1;
      int c = k0 - KCONV + cq * 4;
      pkr = *(const uint2*)&xid[((size_t)(b * HWSZ) + y * WW + x0 + ps) * 64 + c];
    }
  };
  auto commit = [&](int buf) {
    uint2 pk;
    if (!isres) {
      f32x2 v0 = up2(t00.x) * wgt.x + up2(t01.x) * wgt.y
               + up2(t10.x) * wgt.z + up2(t11.x) * wgt.w;
      f32x2 v1 = up2(t00.y) * wgt.x + up2(t01.y) * wgt.y
               + up2(t10.y) * wgt.z + up2(t11.y) * wgt.w;
      pk.x = pack2bf(v0[0], v0[1]);
      pk.y = pack2bf(v1[0], v1[1]);
    } else {
      pk = pkr;
    }
    *(s16x8*)&wlds[buf * 5120 + (tid >> 2) * 40 + (tid & 3) * 8] = wreg;
    *(uint2*)&vlds[buf * 2560 + ps * 40 + cq * 4] = pk;
  };

  __syncthreads();        // descriptors ready
  issue(0);
  commit(0);
  __syncthreads();
  const int NC = KTOT >> 5;
  for (int ch = 0; ch < NC; ch++) {
    int cur = ch & 1;
    bool has = (ch + 1) < NC;
    if (has) issue((ch + 1) << 5);
    bf16x8 bfr = *(const bf16x8*)&vlds[cur * 2560 + (ptile * 16 + l15) * 40 + quad * 8];
#pragma unroll
    for (int ot = 0; ot < 4; ot++) {
      bf16x8 afr = *(const bf16x8*)&wlds[cur * 5120 + (og * 64 + ot * 16 + l15) * 40 + quad * 8];
      acc[ot] = __builtin_amdgcn_mfma_f32_16x16x32_bf16(afr, bfr, acc[ot], 0, 0, 0);
    }
    if (has) commit(cur ^ 1);
    __syncthreads();
  }

  if (mode == 1) {
    int px_ = x0 + ptile * 16 + l15;
#pragma unroll
    for (int ot = 0; ot < 4; ot++) {
#pragma unroll
      for (int r = 0; r < 4; r++) {
        int o = og * 64 + ot * 16 + quad * 4 + r;
        outf[(size_t)(b * COUT + o) * HWSZ + y * WW + px_] =
            fmaxf(acc[ot][r] + cbv[o], 0.f);
      }
    }
  } else {
    // h1 NHWC bf16 via LDS transpose (overlays dead descriptor region)
    int pl = ptile * 16 + l15;
#pragma unroll
    for (int ot = 0; ot < 4; ot++) {
      s16x4 t4;
#pragma unroll
      for (int r = 0; r < 4; r++) {
        int o = og * 64 + ot * 16 + quad * 4 + r;
        t4[r] = tobf(fmaxf(acc[ot][r] + cbv[o], 0.f));
      }
      *(s16x4*)&trans[pl * 136 + og * 64 + ot * 16 + quad * 4] = t4;
    }
    __syncthreads();
    int pw = tid >> 3, cseg = (tid & 7) * 16;
    u16x8 a = *(const u16x8*)&trans[pw * 136 + cseg];
    u16x8 b8 = *(const u16x8*)&trans[pw * 136 + cseg + 8];
    size_t gb = ((size_t)(b * HWSZ) + y * WW + x0 + pw) * 128 + cseg;
    *(u16x8*)&outb[gb] = a;
    *(u16x8*)&outb[gb + 8] = b8;
  }
}

// ---------------------------------------------------------------------------
extern "C" void kernel_launch(void* const* d_in, const int* in_sizes, int n_in,
                              void* d_out, int out_size, void* d_ws, size_t ws_size,
                              hipStream_t stream) {
  const float* x        = (const float*)d_in[0];
  const float* dc1_offw = (const float*)d_in[1];
  const float* dc1_offb = (const float*)d_in[2];
  const float* dc1_w    = (const float*)d_in[3];
  const float* bn1_g    = (const float*)d_in[4];
  const float* bn1_b    = (const float*)d_in[5];
  const float* bn1_m    = (const float*)d_in[6];
  const float* bn1_v    = (const float*)d_in[7];
  const float* dc2_offw = (const float*)d_in[8];
  const float* dc2_offb = (const float*)d_in[9];
  const float* dc2_w    = (const float*)d_in[10];
  const float* bn2_g    = (const float*)d_in[11];
  const float* bn2_b    = (const float*)d_in[12];
  const float* bn2_m    = (const float*)d_in[13];
  const float* bn2_v    = (const float*)d_in[14];
  const float* id_w     = (const float*)d_in[15];
  const float* id_b     = (const float*)d_in[16];
  const float* bn3_g    = (const float*)d_in[17];
  const float* bn3_b    = (const float*)d_in[18];
  const float* bn3_m    = (const float*)d_in[19];
  const float* bn3_v    = (const float*)d_in[20];

  float* wsf = (float*)d_ws;
  float* off1 = wsf;                                   // 2*18*16384 f
  float* off2 = off1 + (size_t)BB * 18 * HWSZ;
  float* cb1  = off2 + (size_t)BB * 18 * HWSZ;
  float* cb2  = cb1 + 128;
  unsigned short* xbf = (unsigned short*)(cb2 + 128);  // NHWC (B,H,W,64)
  unsigned short* h1  = xbf + (size_t)BB * HWSZ * 64;  // NHWC (B,H,W,128)
  short* wbf1  = (short*)(h1 + (size_t)BB * HWSZ * COUT);  // 128 x 576
  short* wbf2  = wbf1 + (size_t)128 * 576;             // 128 x 1216
  short* woff1 = wbf2 + (size_t)128 * 1216;            // 32 x 576
  short* woff2 = woff1 + (size_t)32 * 576;             // 32 x 1152

  const int K1 = 576, K2 = 1152, KT2 = 1216;

  hipLaunchKernelGGL(prep_all_kernel, dim3((PA5 + 255) / 256), dim3(256), 0, stream,
                     dc1_w, dc2_w, id_w, dc1_offw, dc2_offw,
                     bn1_g, bn1_b, bn1_m, bn1_v, bn2_g, bn2_b, bn2_m, bn2_v,
                     bn3_g, bn3_b, bn3_m, bn3_v, id_b,
                     wbf1, wbf2, woff1, woff2, cb1, cb2);
  hipLaunchKernelGGL(xcast_kernel, dim3(BB * HWSZ / 64), dim3(256), 0, stream, x, xbf);

  // --- layer 1 ---
  hipLaunchKernelGGL(offconv_mfma_kernel, dim3(1024), dim3(256), 0, stream,
                     xbf, woff1, dc1_offb, off1, 6);
  hipLaunchKernelGGL(deform_mfma_kernel, dim3(512), dim3(512), 0, stream,
                     xbf, off1, wbf1, cb1, (const unsigned short*)nullptr,
                     (float*)nullptr, h1, 6, K1, K1, 0);
  // --- layer 2 (identity residual folded into GEMM) ---
  hipLaunchKernelGGL(offconv_mfma_kernel, dim3(1024), dim3(256), 0, stream,
                     h1, woff2, dc2_offb, off2, 7);
  hipLaunchKernelGGL(deform_mfma_kernel, dim3(512), dim3(512), 0, stream,
                     h1, off2, wbf2, cb2, xbf, (float*)d_out,
                     (unsigned short*)nullptr, 7, K2, KT2, 1);
}